// Round 20
// baseline (107.907 us; speedup 1.0000x reference)
//
#include <hip/hip_runtime.h>
#include <hip/hip_bf16.h>
#include <math.h>

#define N_ROWS 32768
#define H      512
#define GV     640
#define V      320
#define DG     128
#define BM     64           // rows per block (2 wave-rows of 32)
#define NT     16           // K-steps of 32 (H=512)

typedef __attribute__((ext_vector_type(16))) float f32x16;
typedef __attribute__((ext_vector_type(8)))  short short8v;  // 8 bf16

static __device__ __forceinline__ short f2bf(float f) {      // fp32 -> bf16 RNE
    unsigned int u = __float_as_uint(f);
    u += 0x7fffu + ((u >> 16) & 1u);
    return (short)(u >> 16);
}

// async global->LDS DMA, 16 B per lane; LDS dest = wave-uniform base + lane*16.
static __device__ __forceinline__ void gload_lds16(const short* g, short* l) {
    __builtin_amdgcn_global_load_lds(
        (const __attribute__((address_space(1))) void*)g,
        (__attribute__((address_space(3))) void*)l, 16, 0, 0);
}

// Merged pack kernel for 32x32x16 fragments (R17-verified).
// blocks [0,160): W -> B-frags: frag (t2,ct): lane l gives B[k=t2*16+8*(l>>5)+i][col=ct*32+(l&31)]
//   wp[(((t2*20+ct)*64+l)*8+i)]; K-step t (k=32) = t2 {2t,2t+1} -> 40KB contiguous slice.
// blocks [160,8352): hidden -> A-frags (in OUT buffer): frag (rt32,t2): lane l gives
//   A[row=rt32*32+(l&31)][k=t2*16+8*(l>>5)+i];  ap[((rt32*32+t2)*64+l)*8+i].
__global__ __launch_bounds__(256)
void pack_wa(const float* __restrict__ W, short* __restrict__ wp,
             const float* __restrict__ hidden, short* __restrict__ ap)
{
    if (blockIdx.x < 160) {
        int gid = blockIdx.x * 256 + threadIdx.x;   // 40960 = 32 t2 * 20 ct * 64 l
        int l   = gid & 63;
        int ct  = (gid >> 6) % 20;
        int t2  = gid / (20 * 64);
        int row = t2 * 16 + 8 * (l >> 5);
        int col = ct * 32 + (l & 31);
        short8v pk;
        #pragma unroll
        for (int i = 0; i < 8; ++i)
            pk[i] = f2bf(W[(size_t)(row + i) * GV + col]);
        *(short8v*)(wp + (size_t)gid * 8) = pk;
    } else {
        int gid = (blockIdx.x - 160) * 256 + threadIdx.x;  // 2,097,152 = 1024 rt32 * 32 t2 * 64 l
        int l    = gid & 63;
        int t2   = (gid >> 6) & 31;
        int rt32 = gid >> 11;
        const float* src = hidden + (size_t)(rt32 * 32 + (l & 31)) * H + t2 * 16 + 8 * (l >> 5);
        float4 x0 = *(const float4*)src;
        float4 x1 = *(const float4*)(src + 4);
        short8v pk;
        pk[0] = f2bf(x0.x); pk[1] = f2bf(x0.y); pk[2] = f2bf(x0.z); pk[3] = f2bf(x0.w);
        pk[4] = f2bf(x1.x); pk[5] = f2bf(x1.y); pk[6] = f2bf(x1.z); pk[7] = f2bf(x1.w);
        *(short8v*)(ap + (size_t)gid * 8) = pk;
    }
}

// Fused: bf16 32x32x16-MFMA logits GEMM + gumbel argmax + softmax marginal + gather.
// 512 threads = 8 waves, wave grid 2(wm) x 4(wn): wave owns 32 rows x 160 cols (5 tiles).
// Per K-step: 10 ds_read_b128 feed 10 MFMAs covering 2x the rows of the 16x16 version
// -> block LDS-read volume halves (R16 was ds_read-volume-bound).
// C layout (m74/m101): col = lane&31, row = (reg&3) + 8*(reg>>2) + 4*(lane>>5).
// LAUNCH_BOUNDS (512,2) — NOT (512,4): R17/R14 showed min-waves=4 makes the allocator
// pin VGPR=64 and spill the 80-reg accumulator (~100MB scratch, 117us); R6/R7 with
// min=2 allocated 100-108 freely. Natural ~110 VGPR -> 4 waves/SIMD -> 2 blocks/CU.
// Gumbel/mask loads AFTER the K-loop (R10: vmcnt in-order). DMA staging (R16).
__global__ __launch_bounds__(512, 2)
void gumbel_vq_main(const short* apack,               // aliases out! (no restrict)
                    const int*   __restrict__ mask,
                    const float* __restrict__ gumbel,
                    const short* __restrict__ wpack,
                    const float* __restrict__ bias,
                    const float* __restrict__ codevec,
                    float* out,                       // aliases apack (no restrict)
                    float* __restrict__ ws)
{
    // 2 x 40KB staging buffers = 81920 B -> 2 blocks/CU.
    __shared__ __align__(16) short sbuf[2][20480];
    // Epilogue structures ALIAS buffer 0: used only after the K-loop's final barrier;
    // last K-iteration (t=15) reads only sbuf[1] — disjoint.
    float4 (*ex)[32]   = (float4 (*)[32])(&sbuf[0][0]);          //  4096 B: per-wave per-row (zm,zi,lm)
    float*  ex2        = (float*)((char*)sbuf + 4096);           //  1024 B: per-wave per-row psum
    float*  mg         = (float*)((char*)sbuf + 5120);           //  5120 B: per-wm marginals
    int   (*rowtab)[2] = (int (*)[2])((char*)sbuf + 10240);      //   512 B: winner idx per row/group

    const int tid = threadIdx.x;
    const int tn  = tid & 63;
    const int wid = tid >> 6;             // 0..7
    const int wm  = wid >> 2;             // 0..1 (row half: 32 rows)
    const int wn  = wid & 3;              // 0..3 (col quadrant: 160 cols)
    const int hi  = tn >> 5;              // lane half (row-offset +4)
    const int ln  = tn & 31;              // lane col within tile
    const int row0 = blockIdx.x * BM;
    const int colbase = wn * 160 + ln;    // this lane's column for tile j=0

    // acc init = bias (all 16 regs of tile j share the lane's column)
    f32x16 acc[5];
    #pragma unroll
    for (int j = 0; j < 5; ++j) {
        float b = bias[colbase + j * 32];
        f32x16 c;
        #pragma unroll
        for (int r = 0; r < 16; ++r) c[r] = b;
        acc[j] = c;
    }

    // A-frag base: rt32 = blockIdx*2 + wm; frag t2 at +t2*512 shorts
    const short* ab = apack + ((size_t)(blockIdx.x * 2 + wm) * 2048 + tn) * 8;

    // ---- prologue: DMA K-step 0 (40KB = 512 threads x 5 x 16B); load A(t2=0,1) ----
    #pragma unroll
    for (int k2 = 0; k2 < 5; ++k2)
        gload_lds16(wpack + (size_t)(tid + k2 * 512) * 8, &sbuf[0][(size_t)(tid + k2 * 512) * 8]);
    short8v a0reg = *(const short8v*)ab;
    short8v a1reg = *(const short8v*)(ab + 512);
    __syncthreads();

    // ---- K-loop: 2-phase LDS pipeline, 10 ds_read_b128 + 10 MFMA(32x32x16) per wave-step ----
    #pragma unroll
    for (int t = 0; t < NT; ++t) {
        const int cur = t & 1;
        short8v an0, an1;
        if (t + 1 < NT) {                 // issue-early: DMA + A loads for step t+1
            const short* wt = wpack + (size_t)(t + 1) * 20480;
            short* bd = &sbuf[cur ^ 1][0];
            #pragma unroll
            for (int k2 = 0; k2 < 5; ++k2)
                gload_lds16(wt + (size_t)(tid + k2 * 512) * 8, bd + (size_t)(tid + k2 * 512) * 8);
            an0 = *(const short8v*)(ab + (size_t)(2 * t + 2) * 512);
            an1 = *(const short8v*)(ab + (size_t)(2 * t + 3) * 512);
        }
        #pragma unroll
        for (int j = 0; j < 5; ++j) {
            short8v b0 = *(const short8v*)(&sbuf[cur][(size_t)((wn * 5 + j) * 64 + tn) * 8]);
            acc[j] = __builtin_amdgcn_mfma_f32_32x32x16_bf16(a0reg, b0, acc[j], 0, 0, 0);
            short8v b1 = *(const short8v*)(&sbuf[cur][(size_t)(((20 + wn * 5 + j)) * 64 + tn) * 8]);
            acc[j] = __builtin_amdgcn_mfma_f32_32x32x16_bf16(a1reg, b1, acc[j], 0, 0, 0);
        }
        if (t + 1 < NT) { a0reg = an0; a1reg = an1; }
        __syncthreads();                  // drains this step's DMA; structural pipeline
    }

    // ---- epilogue: 4 chunks of 8 rows (4 regs x 2 lane-halves) ----
    const int rowbase = row0 + wm * 32;
    const int pw = wid ^ 1;               // group partner ({wn0,wn1}=g0, {wn2,wn3}=g1)
    float part[5];
    #pragma unroll
    for (int j = 0; j < 5; ++j) part[j] = 0.f;

    #pragma unroll
    for (int rc = 0; rc < 4; ++rc) {      // regs r = rc*4+rr; row R = 8*rc + rr + 4*hi
        float lm[4], zm[4]; int zi[4];
        // plain-logit max (g-independent; issued before gumbel loads land)
        #pragma unroll
        for (int rr = 0; rr < 4; ++rr) {
            const int r = rc * 4 + rr;
            float m_ = acc[0][r];
            #pragma unroll
            for (int j = 1; j < 5; ++j) m_ = fmaxf(m_, acc[j][r]);
            lm[rr] = m_;
        }
        // gumbel argmax: cols colbase+32j ascending -> strict '>' keeps first index
        #pragma unroll
        for (int rr = 0; rr < 4; ++rr) {
            const int r = rc * 4 + rr;
            const int R = 8 * rc + rr + 4 * hi;
            const float* gp = gumbel + (size_t)(rowbase + R) * GV + colbase;
            zm[rr] = acc[0][r] + gp[0]; zi[rr] = colbase;
            #pragma unroll
            for (int j = 1; j < 5; ++j) {
                float zj = acc[j][r] + gp[32 * j];
                if (zj > zm[rr]) { zm[rr] = zj; zi[rr] = colbase + 32 * j; }
            }
        }
        // 32-lane butterfly within lane-half (d<=16 keeps hi fixed)
        #pragma unroll
        for (int d = 16; d >= 1; d >>= 1) {
            #pragma unroll
            for (int rr = 0; rr < 4; ++rr) {
                float oz = __shfl_xor(zm[rr], d, 64); int oi = __shfl_xor(zi[rr], d, 64);
                if (oz > zm[rr] || (oz == zm[rr] && oi < zi[rr])) { zm[rr] = oz; zi[rr] = oi; }
                lm[rr] = fmaxf(lm[rr], __shfl_xor(lm[rr], d, 64));
            }
        }
        // exchange with partner wave (chunks touch disjoint R rows of ex)
        if (ln == 0) {
            #pragma unroll
            for (int rr = 0; rr < 4; ++rr) {
                const int R = 8 * rc + rr + 4 * hi;
                float4 e; e.x = zm[rr]; e.y = __int_as_float(zi[rr]); e.z = lm[rr]; e.w = 0.f;
                ex[wid][R] = e;
            }
        }
        __syncthreads();
        #pragma unroll
        for (int rr = 0; rr < 4; ++rr) {
            const int R = 8 * rc + rr + 4 * hi;
            float4 e = ex[pw][R];
            float pz = e.x; int pi = __float_as_int(e.y);
            if (pz > zm[rr] || (pz == zm[rr] && pi < zi[rr])) { zm[rr] = pz; zi[rr] = pi; }
            lm[rr] = fmaxf(lm[rr], e.z);
        }
        // softmax partial sums over this wave's 160 cols
        float ps[4];
        #pragma unroll
        for (int rr = 0; rr < 4; ++rr) {
            const int r = rc * 4 + rr;
            float s = 0.f;
            #pragma unroll
            for (int j = 0; j < 5; ++j) s += __expf(acc[j][r] - lm[rr]);
            ps[rr] = s;
        }
        #pragma unroll
        for (int d = 16; d >= 1; d >>= 1)
            #pragma unroll
            for (int rr = 0; rr < 4; ++rr)
                ps[rr] += __shfl_xor(ps[rr], d, 64);
        if (ln == 0) {
            #pragma unroll
            for (int rr = 0; rr < 4; ++rr)
                ex2[wid * 32 + (8 * rc + rr + 4 * hi)] = ps[rr];
        }
        __syncthreads();
        float inv[4];
        #pragma unroll
        for (int rr = 0; rr < 4; ++rr) {
            const int R = 8 * rc + rr + 4 * hi;
            float mrow = (mask[rowbase + R] != 0) ? 1.f : 0.f;
            inv[rr] = mrow / (ps[rr] + ex2[pw * 32 + R]);
        }
        // marginal contribution (recompute exp: keeps pm out of registers)
        #pragma unroll
        for (int j = 0; j < 5; ++j) {
            #pragma unroll
            for (int rr = 0; rr < 4; ++rr) {
                const int r = rc * 4 + rr;
                part[j] += __expf(acc[j][r] - lm[rr]) * inv[rr];
            }
        }
        // winning indices -> row table (one wave per group: wn==0 -> g0, wn==2 -> g1)
        if ((wn == 0 || wn == 2) && ln == 0) {
            int grp = wn >> 1;
            #pragma unroll
            for (int rr = 0; rr < 4; ++rr)
                rowtab[wm * 32 + (8 * rc + rr + 4 * hi)][grp] = zi[rr] - grp * V;
        }
    }

    // combine lane-halves (same col, other 16 rows), write marginals
    #pragma unroll
    for (int j = 0; j < 5; ++j)
        part[j] += __shfl_xor(part[j], 32, 64);
    if (hi == 0) {
        #pragma unroll
        for (int j = 0; j < 5; ++j)
            mg[wm * GV + colbase + 32 * j] = part[j];  // wn slices + wm rows disjoint
    }
    __syncthreads();

    // ---- marginal atomics, mask count, codevector gather ----
    for (int c = tid; c < GV; c += 512)
        atomicAdd(&ws[c], mg[c] + mg[GV + c]);
    if (wid == 0) {
        int mr = (mask[row0 + tn] != 0);
        unsigned long long b = __ballot(mr);
        if (tn == 0) atomicAdd(&ws[GV], (float)__popcll(b));
    }
    {
        const int row = tid >> 3;          // 0..63
        const int six = tid & 7;
        #pragma unroll
        for (int i = 0; i < 8; ++i) {
            int e4  = six + 8 * i;         // 0..63 float4s of the 256-float out row
            int grp = e4 >> 5;
            int off = e4 & 31;
            int idx = rowtab[row][grp];
            float4 vv = ((const float4*)(codevec + ((size_t)grp * V + idx) * DG))[off];
            ((float4*)(out + (size_t)(row0 + row) * (2 * DG)))[e4] = vv;
        }
    }
}

__global__ void gumbel_vq_finalize(const float* __restrict__ ws, float* __restrict__ out)
{
    __shared__ float red[GV];
    int t = threadIdx.x;
    float cnt = ws[GV];
    float p = ws[t] / cnt;
    red[t] = p * logf(p + 1e-7f);
    __syncthreads();
    if (t == 0) {
        float e0 = 0.f, e1 = 0.f;
        for (int i = 0; i < V; ++i)  e0 += red[i];
        for (int i = V; i < GV; ++i) e1 += red[i];
        out[(size_t)N_ROWS * 2 * DG] = expf(-e0) + expf(-e1);
    }
}

extern "C" void kernel_launch(void* const* d_in, const int* in_sizes, int n_in,
                              void* d_out, int out_size, void* d_ws, size_t ws_size,
                              hipStream_t stream)
{
    const float* hidden  = (const float*)d_in[0];
    const int*   mask    = (const int*)  d_in[1];
    const float* gumbel  = (const float*)d_in[2];
    const float* W       = (const float*)d_in[3];
    const float* bias    = (const float*)d_in[4];
    const float* codevec = (const float*)d_in[5];
    float* out = (float*)d_out;
    float* ws  = (float*)d_ws;
    // ws layout: [0..639] marginal, [640] mask count, +4096B: W bf16 fragment pack (655 KB).
    // A bf16 fragment pack (33,554,432 B) lives in the OUT buffer (fits; barrier-ordered:
    // each block reads only its own rows' apack before writing the same rows of out).
    short* wpack = (short*)((char*)d_ws + 4096);
    short* apack = (short*)d_out;

    hipMemsetAsync(d_ws, 0, (GV + 1) * sizeof(float), stream);
    pack_wa<<<8352, 256, 0, stream>>>(W, wpack, hidden, apack);
    gumbel_vq_main<<<N_ROWS / BM, 512, 0, stream>>>(apack, mask, gumbel, wpack, bias, codevec, out, ws);
    gumbel_vq_finalize<<<1, GV, 0, stream>>>(ws, out);
}

// Round 21
// 90.879 us; speedup vs baseline: 1.1874x; 1.1874x over previous
//
#include <hip/hip_runtime.h>
#include <hip/hip_bf16.h>
#include <math.h>

#define N_ROWS 32768
#define H      512
#define GV     640
#define V      320
#define DG     128
#define BM     64           // rows per block (4 row-tiles of 16, one per wave-row)
#define NT     16           // K-steps of 32 (H=512)

typedef __attribute__((ext_vector_type(4))) float f32x4;
typedef __attribute__((ext_vector_type(8))) short short8v;   // 8 bf16

static __device__ __forceinline__ short f2bf(float f) {      // fp32 -> bf16 RNE
    unsigned int u = __float_as_uint(f);
    u += 0x7fffu + ((u >> 16) & 1u);
    return (short)(u >> 16);
}

// async global->LDS DMA, 16 B per lane; LDS dest must be wave-uniform base + lane*16
// (ours is: dest byte = tid*16 + const). Counted by vmcnt; drained by __syncthreads().
static __device__ __forceinline__ void gload_lds16(const short* g, short* l) {
    __builtin_amdgcn_global_load_lds(
        (const __attribute__((address_space(1))) void*)g,
        (__attribute__((address_space(3))) void*)l, 16, 0, 0);
}

// Merged pack kernel (one launch instead of two):
// blocks [0,160):    pack W  (fp32 [512][640]) -> bf16 B-fragments, step-contiguous:
//   frag (t, ct): lane l supplies B[k=t*32+8*(l>>4)+i][col=ct*16+(l&15)], i=0..7;
//   wp[(((t*40+ct)*64+l)*8+i)] -> step t's 40 KB slice is CONTIGUOUS (linear LDS staging).
// blocks [160,8352): pack hidden (fp32 [32768][512]) -> bf16 A-fragments (in OUT buffer):
//   frag (rt, t): lane l supplies A[row=rt*16+(l&15)][k=t*32+8*(l>>4)+i], i=0..7.
__global__ __launch_bounds__(256)
void pack_wa(const float* __restrict__ W, short* __restrict__ wp,
             const float* __restrict__ hidden, short* __restrict__ ap)
{
    if (blockIdx.x < 160) {
        int gid = blockIdx.x * 256 + threadIdx.x;   // 40960 = 16 t * 40 ct * 64 l
        int l   = gid & 63;
        int ct  = (gid >> 6) % 40;
        int t   = gid / (40 * 64);
        int row = t * 32 + 8 * (l >> 4);
        int col = ct * 16 + (l & 15);
        short8v pk;
        #pragma unroll
        for (int i = 0; i < 8; ++i)
            pk[i] = f2bf(W[(size_t)(row + i) * GV + col]);
        *(short8v*)(wp + (size_t)gid * 8) = pk;
    } else {
        int gid = (blockIdx.x - 160) * 256 + threadIdx.x;   // 2,097,152 = 2048 rt * 16 t * 64 l
        int l   = gid & 63;
        int t   = (gid >> 6) & 15;
        int rt  = gid >> 10;
        const float* src = hidden + (size_t)(rt * 16 + (l & 15)) * H + t * 32 + 8 * (l >> 4);
        float4 x0 = *(const float4*)src;
        float4 x1 = *(const float4*)(src + 4);
        short8v pk;
        pk[0] = f2bf(x0.x); pk[1] = f2bf(x0.y); pk[2] = f2bf(x0.z); pk[3] = f2bf(x0.w);
        pk[4] = f2bf(x1.x); pk[5] = f2bf(x1.y); pk[6] = f2bf(x1.z); pk[7] = f2bf(x1.w);
        *(short8v*)(ap + (size_t)gid * 8) = pk;
    }
}

// Fused: bf16-MFMA logits GEMM + gumbel argmax + softmax marginal + codevector gather.
// 1024 threads = 16 waves, wave grid 4(M) x 4(N), BM=64: each wave owns ONE 16-row tile.
// K-loop: 2-phase double-buffered W staging via global_load_lds width=16 (async DMA, no
// VGPR round-trip, no ds_write phase — the compiler never auto-emits this). Loads for
// step t+1 issue at iter-t top; ds_reads+MFMAs of step t cover their latency; the
// step-end __syncthreads() drains vmcnt. Gumbel/mask loads stay AFTER the K-loop
// (R10: vmcnt completion is in-order; cold loads ahead serialize every MFMA).
// NOTE (R17-R20): counted vmcnt, 32x32 MFMA, 2-tile/wave, and A-fusion all measured
// WORSE than this structure — this is the empirical optimum of the explored space.
__global__ __launch_bounds__(1024, 4)
void gumbel_vq_main(const short* apack,               // aliases out! (no restrict)
                    const int*   __restrict__ mask,
                    const float* __restrict__ gumbel,
                    const short* __restrict__ wpack,
                    const float* __restrict__ bias,
                    const float* __restrict__ codevec,
                    float* out,                       // aliases apack (no restrict)
                    float* __restrict__ ws)
{
    // 2 x 40KB staging buffers = 81920 B -> 2 blocks/CU (160 KB LDS).
    __shared__ __align__(16) short sbuf[2][20480];
    // Epilogue structures ALIAS buffer 0 (first ~16 KB): used only after the K-loop's
    // final barrier; the last K-iteration (t=15) reads only sbuf[1] — disjoint.
    float4 (*ex)[16]   = (float4 (*)[16])(&sbuf[0][0]);          //  4096 B: per-wave (zm,zi,lm)
    float*  ex2        = (float*)((char*)sbuf + 4096);           //  1024 B: per-wave psum
    float*  mg         = (float*)((char*)sbuf + 5120);           // 10240 B: per-wm marginals
    int   (*rowtab)[2] = (int (*)[2])((char*)sbuf + 15360);      //   512 B: winner idx/row/group

    const int tid = threadIdx.x;
    const int tn  = tid & 63;
    const int wid = tid >> 6;             // 0..15
    const int wm  = wid >> 2;             // 0..3 (row-tile)
    const int wn  = wid & 3;              // 0..3 (col quadrant)
    const int q   = tn >> 4;
    const int cn  = tn & 15;
    const int row0 = blockIdx.x * BM;
    const int cbase = wn * 160 + cn;      // this lane's column for j=0

    // acc init = bias
    f32x4 acc[10];
    #pragma unroll
    for (int j = 0; j < 10; ++j) {
        float b = bias[cbase + j * 16];
        f32x4 c; c[0] = b; c[1] = b; c[2] = b; c[3] = b;
        acc[j] = c;
    }

    // A-frag base: global row-tile blockIdx*4 + wm
    const short* ab = apack + ((size_t)(blockIdx.x * 4 + wm) * 1024 + tn) * 8;

    // staging split: 2560 x 16B per step over 1024 threads = 2 each + 1 extra for tid<512
    const bool xtra = (tid < 512);        // wave-uniform

    // ---- prologue: DMA K-step 0 into sbuf[0]; load A(0) ----
    gload_lds16(wpack + (size_t)tid * 8,          &sbuf[0][(size_t)tid * 8]);
    gload_lds16(wpack + (size_t)(tid + 1024) * 8, &sbuf[0][(size_t)(tid + 1024) * 8]);
    if (xtra)
        gload_lds16(wpack + (size_t)(tid + 2048) * 8, &sbuf[0][(size_t)(tid + 2048) * 8]);
    short8v areg = *(const short8v*)ab;
    __syncthreads();                      // drains the DMA (vmcnt) + barrier

    // ---- K-loop: 2-phase LDS pipeline, DMA staging + 10 ds_read_b128 + 10 MFMA ----
    #pragma unroll
    for (int t = 0; t < NT; ++t) {
        const int cur = t & 1;
        short8v anx;
        if (t + 1 < NT) {                 // issue-early: async DMA for step t+1
            const short* wt = wpack + (size_t)(t + 1) * 20480;
            short* bd = &sbuf[cur ^ 1][0];
            gload_lds16(wt + (size_t)tid * 8,          bd + (size_t)tid * 8);
            gload_lds16(wt + (size_t)(tid + 1024) * 8, bd + (size_t)(tid + 1024) * 8);
            if (xtra)
                gload_lds16(wt + (size_t)(tid + 2048) * 8, bd + (size_t)(tid + 2048) * 8);
            anx = *(const short8v*)(ab + (size_t)(t + 1) * 512);
        }
        const short* bufc = &sbuf[cur][(size_t)(wn * 640 + tn) * 8];
        #pragma unroll
        for (int j = 0; j < 10; ++j) {
            short8v bf = *(const short8v*)(bufc + j * 512);
            acc[j] = __builtin_amdgcn_mfma_f32_16x16x32_bf16(areg, bf, acc[j], 0, 0, 0);
        }
        if (t + 1 < NT) areg = anx;
        __syncthreads();                  // drains this step's DMA; structural pipeline
    }

    // ---- NOW issue gumbel + mask loads (fragment layout); lm-reduction covers them ----
    const int rowbase = row0 + wm * 16;
    float g[4][10];
    #pragma unroll
    for (int r = 0; r < 4; ++r) {
        const float* gp = gumbel + (size_t)(rowbase + 4 * q + r) * GV + cbase;
        #pragma unroll
        for (int j = 0; j < 10; ++j) g[r][j] = gp[j * 16];
    }
    float mrow[4];
    #pragma unroll
    for (int r = 0; r < 4; ++r)
        mrow[r] = (mask[rowbase + 4 * q + r] != 0) ? 1.f : 0.f;

    // g-independent: plain-logit max, local chain + 16-lane butterfly
    float lm[4];
    #pragma unroll
    for (int r = 0; r < 4; ++r) {
        lm[r] = acc[0][r];
        #pragma unroll
        for (int j = 1; j < 10; ++j) lm[r] = fmaxf(lm[r], acc[j][r]);
    }
    #pragma unroll
    for (int d = 8; d >= 1; d >>= 1)
        #pragma unroll
        for (int r = 0; r < 4; ++r)
            lm[r] = fmaxf(lm[r], __shfl_xor(lm[r], d, 64));

    // g-dependent: argmax of logits+gumbel (col = cbase+16j ascending -> '>' keeps first idx)
    float zm[4]; int zi[4];
    #pragma unroll
    for (int r = 0; r < 4; ++r) {
        zm[r] = acc[0][r] + g[r][0]; zi[r] = cbase;
        #pragma unroll
        for (int j = 1; j < 10; ++j) {
            float zj = acc[j][r] + g[r][j];
            if (zj > zm[r]) { zm[r] = zj; zi[r] = cbase + 16 * j; }
        }
    }
    #pragma unroll
    for (int d = 8; d >= 1; d >>= 1) {
        #pragma unroll
        for (int r = 0; r < 4; ++r) {
            float oz = __shfl_xor(zm[r], d, 64); int oi = __shfl_xor(zi[r], d, 64);
            if (oz > zm[r] || (oz == zm[r] && oi < zi[r])) { zm[r] = oz; zi[r] = oi; }
        }
    }

    // exchange wave-level stats with group partner (wid^1: wn pairs {0,1},{2,3})
    if (cn == 0) {
        #pragma unroll
        for (int r = 0; r < 4; ++r) {
            float4 e; e.x = zm[r]; e.y = __int_as_float(zi[r]); e.z = lm[r]; e.w = 0.f;
            ex[wid][4 * q + r] = e;
        }
    }
    __syncthreads();
    const int pw = wid ^ 1;
    #pragma unroll
    for (int r = 0; r < 4; ++r) {
        float4 e = ex[pw][4 * q + r];
        float pz = e.x; int pi = __float_as_int(e.y);
        if (pz > zm[r] || (pz == zm[r] && pi < zi[r])) { zm[r] = pz; zi[r] = pi; }
        lm[r] = fmaxf(lm[r], e.z);
    }

    // softmax numerators with group max; wave-level partial sums
    float pm[4][10], ps[4];
    #pragma unroll
    for (int r = 0; r < 4; ++r) {
        ps[r] = 0.f;
        #pragma unroll
        for (int j = 0; j < 10; ++j) {
            float p = __expf(acc[j][r] - lm[r]);
            pm[r][j] = p; ps[r] += p;
        }
    }
    #pragma unroll
    for (int d = 8; d >= 1; d >>= 1)
        #pragma unroll
        for (int r = 0; r < 4; ++r)
            ps[r] += __shfl_xor(ps[r], d, 64);

    if (cn == 0) {
        #pragma unroll
        for (int r = 0; r < 4; ++r) ex2[wid * 16 + 4 * q + r] = ps[r];
    }
    __syncthreads();
    float inv[4];
    #pragma unroll
    for (int r = 0; r < 4; ++r)
        inv[r] = mrow[r] / (ps[r] + ex2[pw * 16 + 4 * q + r]);

    // marginal column partials: this wave's 16 rows, then across q (lanes sharing cn)
    float part[10];
    #pragma unroll
    for (int j = 0; j < 10; ++j) {
        part[j] = pm[0][j] * inv[0] + pm[1][j] * inv[1] + pm[2][j] * inv[2] + pm[3][j] * inv[3];
        part[j] += __shfl_xor(part[j], 16, 64);
        part[j] += __shfl_xor(part[j], 32, 64);
    }
    if (q == 0) {
        #pragma unroll
        for (int j = 0; j < 10; ++j)
            mg[wm * GV + cbase + 16 * j] = part[j];   // wn slices disjoint; wm rows disjoint
    }
    // winning indices -> row table (one wave per group: wn==0 -> g0, wn==2 -> g1)
    if ((wn == 0 || wn == 2) && cn == 0) {
        int grp = wn >> 1;
        #pragma unroll
        for (int r = 0; r < 4; ++r)
            rowtab[wm * 16 + 4 * q + r][grp] = zi[r] - grp * V;
    }
    __syncthreads();

    // ---- marginal atomics, mask count, codevector gather ----
    if (tid < GV)
        atomicAdd(&ws[tid], mg[tid] + mg[GV + tid] + mg[2 * GV + tid] + mg[3 * GV + tid]);
    if (wid == 0) {
        int mr = (mask[row0 + tn] != 0);
        unsigned long long b = __ballot(mr);
        if (tn == 0) atomicAdd(&ws[GV], (float)__popcll(b));
    }
    {
        const int row = tid >> 4;          // 0..63
        const int six = tid & 15;
        #pragma unroll
        for (int i = 0; i < 4; ++i) {
            int e4  = six + 16 * i;        // 0..63 float4s of the 256-float out row
            int grp = e4 >> 5;
            int off = e4 & 31;
            int idx = rowtab[row][grp];
            float4 vv = ((const float4*)(codevec + ((size_t)grp * V + idx) * DG))[off];
            ((float4*)(out + (size_t)(row0 + row) * (2 * DG)))[e4] = vv;
        }
    }
}

__global__ void gumbel_vq_finalize(const float* __restrict__ ws, float* __restrict__ out)
{
    __shared__ float red[GV];
    int t = threadIdx.x;
    float cnt = ws[GV];
    float p = ws[t] / cnt;
    red[t] = p * logf(p + 1e-7f);
    __syncthreads();
    if (t == 0) {
        float e0 = 0.f, e1 = 0.f;
        for (int i = 0; i < V; ++i)  e0 += red[i];
        for (int i = V; i < GV; ++i) e1 += red[i];
        out[(size_t)N_ROWS * 2 * DG] = expf(-e0) + expf(-e1);
    }
}

extern "C" void kernel_launch(void* const* d_in, const int* in_sizes, int n_in,
                              void* d_out, int out_size, void* d_ws, size_t ws_size,
                              hipStream_t stream)
{
    const float* hidden  = (const float*)d_in[0];
    const int*   mask    = (const int*)  d_in[1];
    const float* gumbel  = (const float*)d_in[2];
    const float* W       = (const float*)d_in[3];
    const float* bias    = (const float*)d_in[4];
    const float* codevec = (const float*)d_in[5];
    float* out = (float*)d_out;
    float* ws  = (float*)d_ws;
    // ws layout: [0..639] marginal, [640] mask count, +4096B: W bf16 fragment pack (655 KB).
    // A bf16 fragment pack (33,554,432 B) lives in the OUT buffer (fits; barrier-ordered:
    // each block reads only its own rows' apack before its barriers, writes out after;
    // per-row byte ranges of apack and out coincide, so blocks never alias each other).
    short* wpack = (short*)((char*)d_ws + 4096);
    short* apack = (short*)d_out;

    hipMemsetAsync(d_ws, 0, (GV + 1) * sizeof(float), stream);
    pack_wa<<<8352, 256, 0, stream>>>(W, wpack, hidden, apack);
    gumbel_vq_main<<<N_ROWS / BM, 1024, 0, stream>>>(apack, mask, gumbel, wpack, bias, codevec, out, ws);
    gumbel_vq_finalize<<<1, GV, 0, stream>>>(ws, out);
}